// Round 7
// baseline (1695.931 us; speedup 1.0000x reference)
//
#include <hip/hip_runtime.h>

#define N_NODES 50000
#define N_EDGES 800000
#define SCAN_NB ((N_NODES + 255) / 256)
#define AGG_NB 256  // dst nodes per aggregate block (power of 2: dlocal = dst & 255)

// ---------- CSR build ----------

__global__ __launch_bounds__(256) void count_kernel(const int* __restrict__ dst,
                                                    int* __restrict__ cnt, int nedges) {
    int e = blockIdx.x * 256 + threadIdx.x;
    if (e < nedges) atomicAdd(&cnt[dst[e]], 1);
}

__device__ __forceinline__ int wave_incl_scan(int v, int lane) {
#pragma unroll
    for (int off = 1; off < 64; off <<= 1) {
        int t = __shfl_up(v, off, 64);
        if (lane >= off) v += t;
    }
    return v;
}

__global__ __launch_bounds__(256) void scanA_kernel(const int* __restrict__ cnt,
                                                    int* __restrict__ partials, int n) {
    const int i = blockIdx.x * 256 + threadIdx.x;
    const int lane = threadIdx.x & 63;
    const int w = threadIdx.x >> 6;
    int v = (i < n) ? cnt[i] : 0;
    int s = wave_incl_scan(v, lane);
    __shared__ int ws[4];
    if (lane == 63) ws[w] = s;
    __syncthreads();
    if (threadIdx.x == 0) partials[blockIdx.x] = ws[0] + ws[1] + ws[2] + ws[3];
}

__global__ __launch_bounds__(256) void scanB_kernel(int* __restrict__ partials, int nb) {
    const int i = threadIdx.x;
    const int lane = i & 63;
    const int w = i >> 6;
    int v = (i < nb) ? partials[i] : 0;
    int s = wave_incl_scan(v, lane);
    __shared__ int ws[4];
    if (lane == 63) ws[w] = s;
    __syncthreads();
    int add = 0;
#pragma unroll
    for (int k = 0; k < 4; ++k)
        if (k < w) add += ws[k];
    if (i < nb) partials[i] = s + add - v;  // exclusive
}

__global__ __launch_bounds__(256) void scanC_kernel(const int* __restrict__ cnt,
                                                    const int* __restrict__ partials,
                                                    int* __restrict__ rowptr,
                                                    int* __restrict__ cursor,
                                                    float* __restrict__ norm, int n) {
    const int i = blockIdx.x * 256 + threadIdx.x;
    const int lane = threadIdx.x & 63;
    const int w = threadIdx.x >> 6;
    int v = (i < n) ? cnt[i] : 0;
    int s = wave_incl_scan(v, lane);
    __shared__ int ws[4];
    if (lane == 63) ws[w] = s;
    __syncthreads();
    int add = partials[blockIdx.x];
#pragma unroll
    for (int k = 0; k < 4; ++k)
        if (k < w) add += ws[k];
    if (i < n) {
        int excl = s + add - v;
        rowptr[i] = excl;
        cursor[i] = excl;
        norm[i] = v > 0 ? rsqrtf((float)v) : 0.0f;
        if (i == n - 1) rowptr[n] = excl + v;
    }
}

// Writes packed (src << 8) | (dst & (AGG_NB-1)) at the CSR slot.
__global__ __launch_bounds__(256) void fill_kernel(const int* __restrict__ src,
                                                   const int* __restrict__ dst,
                                                   int* __restrict__ cursor,
                                                   int* __restrict__ epack, int nedges) {
    int e = blockIdx.x * 256 + threadIdx.x;
    if (e < nedges) {
        int d = dst[e];
        int pos = atomicAdd(&cursor[d], 1);
        epack[pos] = (src[e] << 8) | (d & (AGG_NB - 1));
    }
}

// ---------- GEMM with output row-scale, W staged in LDS ----------
// C_sliced[s][r][c] = norm[r] * sum_k X[r,k] * W[k, s*16+c]
// Output: F/16 slabs of [nrows x 16] floats (slice-major) for L2-local gathers.
template <int OUT>
__global__ __launch_bounds__(256) void gemm_rownorm(const float* __restrict__ X,
                                                    const float* __restrict__ W,
                                                    const float* __restrict__ norm,
                                                    float* __restrict__ C, int nrows) {
    __shared__ float Wlds[128 * OUT];

    const int t = threadIdx.x;

    constexpr int NSTAGE = (128 * OUT) / (256 * 4);
    {
        const float4* __restrict__ Wg = reinterpret_cast<const float4*>(W);
        float4* Wl = reinterpret_cast<float4*>(Wlds);
#pragma unroll
        for (int s = 0; s < NSTAGE; ++s) {
            int idx = s * 256 + t;
            Wl[idx] = Wg[idx];
        }
    }
    __syncthreads();

    const int tc = t & 15;
    const int tr = t >> 4;
    const int rowbase = blockIdx.x * 128 + tr * 8;
    const int lastrow = nrows - 1;

    float4 acc0[8], acc1[8];
#pragma unroll
    for (int i = 0; i < 8; ++i) {
        acc0[i] = make_float4(0.f, 0.f, 0.f, 0.f);
        acc1[i] = make_float4(0.f, 0.f, 0.f, 0.f);
    }

    const float4* __restrict__ X4 = reinterpret_cast<const float4*>(X);
    int rIdx[8];
#pragma unroll
    for (int i = 0; i < 8; ++i) {
        int r = rowbase + i;
        rIdx[i] = r < lastrow ? r : lastrow;
    }

    for (int kk = 0; kk < 32; ++kk) {
        float4 x[8];
#pragma unroll
        for (int i = 0; i < 8; ++i) x[i] = X4[(size_t)rIdx[i] * 32 + kk];
#pragma unroll
        for (int j = 0; j < 4; ++j) {
            const int k = kk * 4 + j;
            const float4 w0 = *reinterpret_cast<const float4*>(&Wlds[k * OUT + tc * 4]);
            float4 w1;
            if constexpr (OUT == 128)
                w1 = *reinterpret_cast<const float4*>(&Wlds[k * OUT + 64 + tc * 4]);
#pragma unroll
            for (int i = 0; i < 8; ++i) {
                const float* xp = reinterpret_cast<const float*>(&x[i]);
                const float xs = xp[j];
                acc0[i].x += xs * w0.x;
                acc0[i].y += xs * w0.y;
                acc0[i].z += xs * w0.z;
                acc0[i].w += xs * w0.w;
                if constexpr (OUT == 128) {
                    acc1[i].x += xs * w1.x;
                    acc1[i].y += xs * w1.y;
                    acc1[i].z += xs * w1.z;
                    acc1[i].w += xs * w1.w;
                }
            }
        }
    }

    float4* __restrict__ C4 = reinterpret_cast<float4*>(C);
    const size_t slab = (size_t)nrows * 4;
    const int s0 = tc >> 2;
    const int w0i = tc & 3;
#pragma unroll
    for (int i = 0; i < 8; ++i) {
        int r = rowbase + i;
        if (r < nrows) {
            const float nm = norm[r];
            float4 o0 = acc0[i];
            o0.x *= nm; o0.y *= nm; o0.z *= nm; o0.w *= nm;
            C4[(size_t)s0 * slab + (size_t)r * 4 + w0i] = o0;
            if constexpr (OUT == 128) {
                float4 o1 = acc1[i];
                o1.x *= nm; o1.y *= nm; o1.z *= nm; o1.w *= nm;
                C4[(size_t)(s0 + 4) * slab + (size_t)r * 4 + w0i] = o1;
            }
        }
    }
}

// ---------- Edge-parallel sliced aggregate with LDS accumulators ----------
// Block = (node window of AGG_NB dsts) x (one 16-col slice). CSR => the window's
// edges are contiguous in epack. 4 lanes per edge (float4 slice), unroll 4,
// clamped unconditional loads; accumulate via LDS atomics into [AGG_NB][20]
// (pad 20 -> aligned float4 epilogue reads, conflict-free).
// slice = blockIdx.x % NSLICE rides block->XCD round-robin for L2 slab locality.
template <int F, bool RELU>
__global__ __launch_bounds__(256) void aggregate_lds(const float* __restrict__ feat,
                                                     const int* __restrict__ rowptr,
                                                     const int* __restrict__ epack,
                                                     const float* __restrict__ norm,
                                                     const float* __restrict__ b,
                                                     float* __restrict__ out, int nnodes) {
    constexpr int NSLICE = F / 16;
    const int slice = blockIdx.x % NSLICE;
    const int nblk  = blockIdx.x / NSLICE;
    const int n0    = nblk * AGG_NB;
    const int nend  = min(nnodes, n0 + AGG_NB);

    __shared__ float acc[AGG_NB * 20];
#pragma unroll
    for (int i = threadIdx.x; i < AGG_NB * 20; i += 256) acc[i] = 0.f;
    __syncthreads();

    const int ebeg = rowptr[n0];
    const int eend = rowptr[nend];
    const int grp  = threadIdx.x >> 2;   // 64 edge-groups per block
    const int l4   = threadIdx.x & 3;    // float4 within the 16-col slice

    const float4* __restrict__ slab4 =
        reinterpret_cast<const float4*>(feat) + (size_t)slice * nnodes * 4;

    for (int eb = ebeg + grp; eb < eend; eb += 256) {
        int pe[4];
        float4 v[4];
        bool ok[4];
#pragma unroll
        for (int i = 0; i < 4; ++i) {
            int e = eb + i * 64;
            ok[i] = e < eend;
            int ec = ok[i] ? e : eend - 1;
            pe[i] = epack[ec];
            v[i] = slab4[(size_t)(pe[i] >> 8) * 4 + l4];
        }
#pragma unroll
        for (int i = 0; i < 4; ++i) {
            if (ok[i]) {
                float* a = &acc[(pe[i] & (AGG_NB - 1)) * 20 + l4 * 4];
                atomicAdd(a + 0, v[i].x);
                atomicAdd(a + 1, v[i].y);
                atomicAdd(a + 2, v[i].z);
                atomicAdd(a + 3, v[i].w);
            }
        }
    }
    __syncthreads();

    // Epilogue: thread t owns node n0+t (AGG_NB == blockDim.x).
    const int node = n0 + threadIdx.x;
    if (node < nend) {
        const float nm = norm[node];
        const float* a = &acc[threadIdx.x * 20];
        float4* o = reinterpret_cast<float4*>(out + (size_t)node * F + slice * 16);
        const float4* bb4 = reinterpret_cast<const float4*>(b) + slice * 4;
#pragma unroll
        for (int q = 0; q < 4; ++q) {
            float4 v = *reinterpret_cast<const float4*>(a + q * 4);
            float4 bb = bb4[q];
            float4 r;
            r.x = v.x * nm + bb.x;
            r.y = v.y * nm + bb.y;
            r.z = v.z * nm + bb.z;
            r.w = v.w * nm + bb.w;
            if (RELU) {
                r.x = fmaxf(r.x, 0.f); r.y = fmaxf(r.y, 0.f);
                r.z = fmaxf(r.z, 0.f); r.w = fmaxf(r.w, 0.f);
            }
            o[q] = r;
        }
    }
}

extern "C" void kernel_launch(void* const* d_in, const int* in_sizes, int n_in,
                              void* d_out, int out_size, void* d_ws, size_t ws_size,
                              hipStream_t stream) {
    const float* features = (const float*)d_in[0];
    const int*   src      = (const int*)d_in[1];
    const int*   dst      = (const int*)d_in[2];
    const float* W1 = (const float*)d_in[3];
    const float* b1 = (const float*)d_in[4];
    const float* W2 = (const float*)d_in[5];
    const float* b2 = (const float*)d_in[6];
    const float* W3 = (const float*)d_in[7];
    const float* b3 = (const float*)d_in[8];
    float* out = (float*)d_out;

    auto align256 = [](size_t x) { return (x + 255) / 256 * 256; };
    char* ws = (char*)d_ws;
    size_t off = 0;
    float* norm     = (float*)(ws + off); off += align256((size_t)N_NODES * 4);
    int*   cnt      = (int*)(ws + off);   off += align256((size_t)N_NODES * 4);
    int*   cursor   = (int*)(ws + off);   off += align256((size_t)N_NODES * 4);
    int*   rowptr   = (int*)(ws + off);   off += align256(((size_t)N_NODES + 1) * 4);
    int*   partials = (int*)(ws + off);   off += align256((size_t)SCAN_NB * 4);
    int*   epack    = (int*)(ws + off);   off += align256((size_t)N_EDGES * 4);
    float* buf0     = (float*)(ws + off); off += (size_t)N_NODES * 128 * 4;
    float* buf1     = (float*)(ws + off);

    const int gemm_blocks = (N_NODES + 127) / 128;
    const int edge_blocks = (N_EDGES + 255) / 256;
    const int node_blks   = (N_NODES + AGG_NB - 1) / AGG_NB;  // 196

    // ---- CSR build + norm ----
    hipMemsetAsync(cnt, 0, (size_t)N_NODES * 4, stream);
    count_kernel<<<edge_blocks, 256, 0, stream>>>(dst, cnt, N_EDGES);
    scanA_kernel<<<SCAN_NB, 256, 0, stream>>>(cnt, partials, N_NODES);
    scanB_kernel<<<1, 256, 0, stream>>>(partials, SCAN_NB);
    scanC_kernel<<<SCAN_NB, 256, 0, stream>>>(cnt, partials, rowptr, cursor, norm, N_NODES);
    fill_kernel<<<edge_blocks, 256, 0, stream>>>(src, dst, cursor, epack, N_EDGES);

    // ---- Layer 1 ----
    gemm_rownorm<128><<<gemm_blocks, 256, 0, stream>>>(features, W1, norm, buf0, N_NODES);
    aggregate_lds<128, true><<<node_blks * 8, 256, 0, stream>>>(buf0, rowptr, epack, norm, b1, buf1, N_NODES);

    // ---- Layer 2 ----
    gemm_rownorm<128><<<gemm_blocks, 256, 0, stream>>>(buf1, W2, norm, buf0, N_NODES);
    aggregate_lds<128, true><<<node_blks * 8, 256, 0, stream>>>(buf0, rowptr, epack, norm, b2, buf1, N_NODES);

    // ---- Layer 3 (64 cols) ----
    gemm_rownorm<64><<<gemm_blocks, 256, 0, stream>>>(buf1, W3, norm, buf0, N_NODES);
    aggregate_lds<64, false><<<node_blks * 4, 256, 0, stream>>>(buf0, rowptr, epack, norm, b3, out, N_NODES);
}

// Round 8
// 334.730 us; speedup vs baseline: 5.0666x; 5.0666x over previous
//
#include <hip/hip_runtime.h>

#define N_NODES 50000
#define N_EDGES 800000
#define SCAN_NB ((N_NODES + 255) / 256)

// ---------- CSR build ----------

__global__ __launch_bounds__(256) void count_kernel(const int* __restrict__ dst,
                                                    int* __restrict__ cnt, int nedges) {
    int e = blockIdx.x * 256 + threadIdx.x;
    if (e < nedges) atomicAdd(&cnt[dst[e]], 1);
}

__device__ __forceinline__ int wave_incl_scan(int v, int lane) {
#pragma unroll
    for (int off = 1; off < 64; off <<= 1) {
        int t = __shfl_up(v, off, 64);
        if (lane >= off) v += t;
    }
    return v;
}

__global__ __launch_bounds__(256) void scanA_kernel(const int* __restrict__ cnt,
                                                    int* __restrict__ partials, int n) {
    const int i = blockIdx.x * 256 + threadIdx.x;
    const int lane = threadIdx.x & 63;
    const int w = threadIdx.x >> 6;
    int v = (i < n) ? cnt[i] : 0;
    int s = wave_incl_scan(v, lane);
    __shared__ int ws[4];
    if (lane == 63) ws[w] = s;
    __syncthreads();
    if (threadIdx.x == 0) partials[blockIdx.x] = ws[0] + ws[1] + ws[2] + ws[3];
}

__global__ __launch_bounds__(256) void scanB_kernel(int* __restrict__ partials, int nb) {
    const int i = threadIdx.x;
    const int lane = i & 63;
    const int w = i >> 6;
    int v = (i < nb) ? partials[i] : 0;
    int s = wave_incl_scan(v, lane);
    __shared__ int ws[4];
    if (lane == 63) ws[w] = s;
    __syncthreads();
    int add = 0;
#pragma unroll
    for (int k = 0; k < 4; ++k)
        if (k < w) add += ws[k];
    if (i < nb) partials[i] = s + add - v;  // exclusive
}

__global__ __launch_bounds__(256) void scanC_kernel(const int* __restrict__ cnt,
                                                    const int* __restrict__ partials,
                                                    int* __restrict__ rowptr,
                                                    int* __restrict__ cursor,
                                                    float* __restrict__ norm, int n) {
    const int i = blockIdx.x * 256 + threadIdx.x;
    const int lane = threadIdx.x & 63;
    const int w = threadIdx.x >> 6;
    int v = (i < n) ? cnt[i] : 0;
    int s = wave_incl_scan(v, lane);
    __shared__ int ws[4];
    if (lane == 63) ws[w] = s;
    __syncthreads();
    int add = partials[blockIdx.x];
#pragma unroll
    for (int k = 0; k < 4; ++k)
        if (k < w) add += ws[k];
    if (i < n) {
        int excl = s + add - v;
        rowptr[i] = excl;
        cursor[i] = excl;
        norm[i] = v > 0 ? rsqrtf((float)v) : 0.0f;
        if (i == n - 1) rowptr[n] = excl + v;
    }
}

__global__ __launch_bounds__(256) void fill_kernel(const int* __restrict__ src,
                                                   const int* __restrict__ dst,
                                                   int* __restrict__ cursor,
                                                   int* __restrict__ esrc, int nedges) {
    int e = blockIdx.x * 256 + threadIdx.x;
    if (e < nedges) {
        int pos = atomicAdd(&cursor[dst[e]], 1);
        esrc[pos] = src[e];
    }
}

// ---------- GEMM with output row-scale, W staged in LDS ----------
// C_sliced[s][r][c] = norm[r] * sum_k X[r,k] * W[k, s*16+c]
// Output: F/16 slabs of [nrows x 16] floats (slice-major) for L2-local gathers.
template <int OUT>
__global__ __launch_bounds__(256) void gemm_rownorm(const float* __restrict__ X,
                                                    const float* __restrict__ W,
                                                    const float* __restrict__ norm,
                                                    float* __restrict__ C, int nrows) {
    __shared__ float Wlds[128 * OUT];

    const int t = threadIdx.x;

    constexpr int NSTAGE = (128 * OUT) / (256 * 4);
    {
        const float4* __restrict__ Wg = reinterpret_cast<const float4*>(W);
        float4* Wl = reinterpret_cast<float4*>(Wlds);
#pragma unroll
        for (int s = 0; s < NSTAGE; ++s) {
            int idx = s * 256 + t;
            Wl[idx] = Wg[idx];
        }
    }
    __syncthreads();

    const int tc = t & 15;
    const int tr = t >> 4;
    const int rowbase = blockIdx.x * 128 + tr * 8;
    const int lastrow = nrows - 1;

    float4 acc0[8], acc1[8];
#pragma unroll
    for (int i = 0; i < 8; ++i) {
        acc0[i] = make_float4(0.f, 0.f, 0.f, 0.f);
        acc1[i] = make_float4(0.f, 0.f, 0.f, 0.f);
    }

    const float4* __restrict__ X4 = reinterpret_cast<const float4*>(X);
    int rIdx[8];
#pragma unroll
    for (int i = 0; i < 8; ++i) {
        int r = rowbase + i;
        rIdx[i] = r < lastrow ? r : lastrow;
    }

    for (int kk = 0; kk < 32; ++kk) {
        float4 x[8];
#pragma unroll
        for (int i = 0; i < 8; ++i) x[i] = X4[(size_t)rIdx[i] * 32 + kk];
#pragma unroll
        for (int j = 0; j < 4; ++j) {
            const int k = kk * 4 + j;
            const float4 w0 = *reinterpret_cast<const float4*>(&Wlds[k * OUT + tc * 4]);
            float4 w1;
            if constexpr (OUT == 128)
                w1 = *reinterpret_cast<const float4*>(&Wlds[k * OUT + 64 + tc * 4]);
#pragma unroll
            for (int i = 0; i < 8; ++i) {
                const float* xp = reinterpret_cast<const float*>(&x[i]);
                const float xs = xp[j];
                acc0[i].x += xs * w0.x;
                acc0[i].y += xs * w0.y;
                acc0[i].z += xs * w0.z;
                acc0[i].w += xs * w0.w;
                if constexpr (OUT == 128) {
                    acc1[i].x += xs * w1.x;
                    acc1[i].y += xs * w1.y;
                    acc1[i].z += xs * w1.z;
                    acc1[i].w += xs * w1.w;
                }
            }
        }
    }

    float4* __restrict__ C4 = reinterpret_cast<float4*>(C);
    const size_t slab = (size_t)nrows * 4;
    const int s0 = tc >> 2;
    const int w0i = tc & 3;
#pragma unroll
    for (int i = 0; i < 8; ++i) {
        int r = rowbase + i;
        if (r < nrows) {
            const float nm = norm[r];
            float4 o0 = acc0[i];
            o0.x *= nm; o0.y *= nm; o0.z *= nm; o0.w *= nm;
            C4[(size_t)s0 * slab + (size_t)r * 4 + w0i] = o0;
            if constexpr (OUT == 128) {
                float4 o1 = acc1[i];
                o1.x *= nm; o1.y *= nm; o1.z *= nm; o1.w *= nm;
                C4[(size_t)(s0 + 4) * slab + (size_t)r * 4 + w0i] = o1;
            }
        }
    }
}

// ---------- Column-sliced gather-aggregate, deep-MLP serial edges ----------
// feat slice-major (F/16 slabs of [nnodes x 16]); slice = blockIdx.x % NSLICE rides
// the round-robin block->XCD dispatch so each XCD's L2 holds one 3.2 MB slab.
// A 4-lane group owns one node at a time: lane = float4 (16B) of the 16-col slice.
// Edge loop unrolled x8 with clamped unconditional loads + masked accumulate into
// 8 independent accumulators -> 8 gathers in flight per lane, mean deg 16 = 2 iters.
template <int F, bool RELU>
__global__ __launch_bounds__(256) void aggregate_sliced(const float* __restrict__ feat,
                                                        const int* __restrict__ rowptr,
                                                        const int* __restrict__ esrc,
                                                        const float* __restrict__ norm,
                                                        const float* __restrict__ b,
                                                        float* __restrict__ out,
                                                        int nnodes, int nchunks) {
    constexpr int NSLICE = F / 16;
    const int slice = blockIdx.x % NSLICE;
    const int chunk = blockIdx.x / NSLICE;
    const int span  = (nnodes + nchunks - 1) / nchunks;
    const int nbeg  = chunk * span;
    const int nend  = min(nnodes, nbeg + span);

    const int grp = threadIdx.x >> 2;   // 64 groups per block
    const int l4  = threadIdx.x & 3;    // float4 within the 16-col slice

    const float4* __restrict__ slab4 =
        reinterpret_cast<const float4*>(feat) + (size_t)slice * nnodes * 4;
    const float4 bb = reinterpret_cast<const float4*>(b)[slice * 4 + l4];

    for (int node = nbeg + grp; node < nend; node += 64) {
        const int beg = rowptr[node];
        const int end = rowptr[node + 1];

        float4 acc[8];
#pragma unroll
        for (int i = 0; i < 8; ++i) acc[i] = make_float4(0.f, 0.f, 0.f, 0.f);

        for (int e = beg; e < end; e += 8) {
            int idx[8];
#pragma unroll
            for (int i = 0; i < 8; ++i) {
                int ee = e + i;
                idx[i] = esrc[ee < end ? ee : end - 1];
            }
            float4 v[8];
#pragma unroll
            for (int i = 0; i < 8; ++i) v[i] = slab4[(size_t)idx[i] * 4 + l4];
#pragma unroll
            for (int i = 0; i < 8; ++i) {
                if (e + i < end) {
                    acc[i].x += v[i].x; acc[i].y += v[i].y;
                    acc[i].z += v[i].z; acc[i].w += v[i].w;
                }
            }
        }

        float4 a;
        a.x = ((acc[0].x + acc[1].x) + (acc[2].x + acc[3].x)) +
              ((acc[4].x + acc[5].x) + (acc[6].x + acc[7].x));
        a.y = ((acc[0].y + acc[1].y) + (acc[2].y + acc[3].y)) +
              ((acc[4].y + acc[5].y) + (acc[6].y + acc[7].y));
        a.z = ((acc[0].z + acc[1].z) + (acc[2].z + acc[3].z)) +
              ((acc[4].z + acc[5].z) + (acc[6].z + acc[7].z));
        a.w = ((acc[0].w + acc[1].w) + (acc[2].w + acc[3].w)) +
              ((acc[4].w + acc[5].w) + (acc[6].w + acc[7].w));

        const float nm = norm[node];
        float4 o;
        o.x = a.x * nm + bb.x;
        o.y = a.y * nm + bb.y;
        o.z = a.z * nm + bb.z;
        o.w = a.w * nm + bb.w;
        if (RELU) {
            o.x = fmaxf(o.x, 0.f); o.y = fmaxf(o.y, 0.f);
            o.z = fmaxf(o.z, 0.f); o.w = fmaxf(o.w, 0.f);
        }
        reinterpret_cast<float4*>(out)[(size_t)node * (F / 4) + slice * 4 + l4] = o;
    }
}

extern "C" void kernel_launch(void* const* d_in, const int* in_sizes, int n_in,
                              void* d_out, int out_size, void* d_ws, size_t ws_size,
                              hipStream_t stream) {
    const float* features = (const float*)d_in[0];
    const int*   src      = (const int*)d_in[1];
    const int*   dst      = (const int*)d_in[2];
    const float* W1 = (const float*)d_in[3];
    const float* b1 = (const float*)d_in[4];
    const float* W2 = (const float*)d_in[5];
    const float* b2 = (const float*)d_in[6];
    const float* W3 = (const float*)d_in[7];
    const float* b3 = (const float*)d_in[8];
    float* out = (float*)d_out;

    auto align256 = [](size_t x) { return (x + 255) / 256 * 256; };
    char* ws = (char*)d_ws;
    size_t off = 0;
    float* norm     = (float*)(ws + off); off += align256((size_t)N_NODES * 4);
    int*   cnt      = (int*)(ws + off);   off += align256((size_t)N_NODES * 4);
    int*   cursor   = (int*)(ws + off);   off += align256((size_t)N_NODES * 4);
    int*   rowptr   = (int*)(ws + off);   off += align256(((size_t)N_NODES + 1) * 4);
    int*   partials = (int*)(ws + off);   off += align256((size_t)SCAN_NB * 4);
    int*   esrc     = (int*)(ws + off);   off += align256((size_t)N_EDGES * 4);
    float* buf0     = (float*)(ws + off); off += (size_t)N_NODES * 128 * 4;
    float* buf1     = (float*)(ws + off);

    const int gemm_blocks = (N_NODES + 127) / 128;
    const int edge_blocks = (N_EDGES + 255) / 256;
    const int chunks128 = 256;   // 256*8 = 2048 blocks
    const int chunks64  = 512;   // 512*4 = 2048 blocks

    // ---- CSR build + norm ----
    hipMemsetAsync(cnt, 0, (size_t)N_NODES * 4, stream);
    count_kernel<<<edge_blocks, 256, 0, stream>>>(dst, cnt, N_EDGES);
    scanA_kernel<<<SCAN_NB, 256, 0, stream>>>(cnt, partials, N_NODES);
    scanB_kernel<<<1, 256, 0, stream>>>(partials, SCAN_NB);
    scanC_kernel<<<SCAN_NB, 256, 0, stream>>>(cnt, partials, rowptr, cursor, norm, N_NODES);
    fill_kernel<<<edge_blocks, 256, 0, stream>>>(src, dst, cursor, esrc, N_EDGES);

    // ---- Layer 1 ----
    gemm_rownorm<128><<<gemm_blocks, 256, 0, stream>>>(features, W1, norm, buf0, N_NODES);
    aggregate_sliced<128, true><<<chunks128 * 8, 256, 0, stream>>>(buf0, rowptr, esrc, norm, b1, buf1, N_NODES, chunks128);

    // ---- Layer 2 ----
    gemm_rownorm<128><<<gemm_blocks, 256, 0, stream>>>(buf1, W2, norm, buf0, N_NODES);
    aggregate_sliced<128, true><<<chunks128 * 8, 256, 0, stream>>>(buf0, rowptr, esrc, norm, b2, buf1, N_NODES, chunks128);

    // ---- Layer 3 (64 cols) ----
    gemm_rownorm<64><<<gemm_blocks, 256, 0, stream>>>(buf1, W3, norm, buf0, N_NODES);
    aggregate_sliced<64, false><<<chunks64 * 4, 256, 0, stream>>>(buf0, rowptr, esrc, norm, b3, out, N_NODES, chunks64);
}

// Round 9
// 302.298 us; speedup vs baseline: 5.6101x; 1.1073x over previous
//
#include <hip/hip_runtime.h>

#define N_NODES 50000
#define N_EDGES 800000
#define SCAN_NB ((N_NODES + 255) / 256)

// ---------- CSR build ----------

__global__ __launch_bounds__(256) void count_kernel(const int* __restrict__ dst,
                                                    int* __restrict__ cnt, int nedges) {
    int e = blockIdx.x * 256 + threadIdx.x;
    if (e < nedges) atomicAdd(&cnt[dst[e]], 1);
}

__device__ __forceinline__ int wave_incl_scan(int v, int lane) {
#pragma unroll
    for (int off = 1; off < 64; off <<= 1) {
        int t = __shfl_up(v, off, 64);
        if (lane >= off) v += t;
    }
    return v;
}

__global__ __launch_bounds__(256) void scanA_kernel(const int* __restrict__ cnt,
                                                    int* __restrict__ partials, int n) {
    const int i = blockIdx.x * 256 + threadIdx.x;
    const int lane = threadIdx.x & 63;
    const int w = threadIdx.x >> 6;
    int v = (i < n) ? cnt[i] : 0;
    int s = wave_incl_scan(v, lane);
    __shared__ int ws[4];
    if (lane == 63) ws[w] = s;
    __syncthreads();
    if (threadIdx.x == 0) partials[blockIdx.x] = ws[0] + ws[1] + ws[2] + ws[3];
}

__global__ __launch_bounds__(256) void scanB_kernel(int* __restrict__ partials, int nb) {
    const int i = threadIdx.x;
    const int lane = i & 63;
    const int w = i >> 6;
    int v = (i < nb) ? partials[i] : 0;
    int s = wave_incl_scan(v, lane);
    __shared__ int ws[4];
    if (lane == 63) ws[w] = s;
    __syncthreads();
    int add = 0;
#pragma unroll
    for (int k = 0; k < 4; ++k)
        if (k < w) add += ws[k];
    if (i < nb) partials[i] = s + add - v;  // exclusive
}

__global__ __launch_bounds__(256) void scanC_kernel(const int* __restrict__ cnt,
                                                    const int* __restrict__ partials,
                                                    int* __restrict__ rowptr,
                                                    int* __restrict__ cursor,
                                                    float* __restrict__ norm, int n) {
    const int i = blockIdx.x * 256 + threadIdx.x;
    const int lane = threadIdx.x & 63;
    const int w = threadIdx.x >> 6;
    int v = (i < n) ? cnt[i] : 0;
    int s = wave_incl_scan(v, lane);
    __shared__ int ws[4];
    if (lane == 63) ws[w] = s;
    __syncthreads();
    int add = partials[blockIdx.x];
#pragma unroll
    for (int k = 0; k < 4; ++k)
        if (k < w) add += ws[k];
    if (i < n) {
        int excl = s + add - v;
        rowptr[i] = excl;
        cursor[i] = excl;
        norm[i] = v > 0 ? rsqrtf((float)v) : 0.0f;
        if (i == n - 1) rowptr[n] = excl + v;
    }
}

__global__ __launch_bounds__(256) void fill_kernel(const int* __restrict__ src,
                                                   const int* __restrict__ dst,
                                                   int* __restrict__ cursor,
                                                   int* __restrict__ esrc, int nedges) {
    int e = blockIdx.x * 256 + threadIdx.x;
    if (e < nedges) {
        int pos = atomicAdd(&cursor[dst[e]], 1);
        esrc[pos] = src[e];
    }
}

// ---------- GEMM with output row-scale, W staged in LDS ----------
// C_sliced[s][r][c] = norm[r] * sum_k X[r,k] * W[k, s*32+c]
// Output: F/32 slabs of [nrows x 32] floats (slice-major, 128 B rows) for
// full-cache-line L2-local gathers.
template <int OUT>
__global__ __launch_bounds__(256) void gemm_rownorm(const float* __restrict__ X,
                                                    const float* __restrict__ W,
                                                    const float* __restrict__ norm,
                                                    float* __restrict__ C, int nrows) {
    __shared__ float Wlds[128 * OUT];

    const int t = threadIdx.x;

    constexpr int NSTAGE = (128 * OUT) / (256 * 4);
    {
        const float4* __restrict__ Wg = reinterpret_cast<const float4*>(W);
        float4* Wl = reinterpret_cast<float4*>(Wlds);
#pragma unroll
        for (int s = 0; s < NSTAGE; ++s) {
            int idx = s * 256 + t;
            Wl[idx] = Wg[idx];
        }
    }
    __syncthreads();

    const int tc = t & 15;
    const int tr = t >> 4;
    const int rowbase = blockIdx.x * 128 + tr * 8;
    const int lastrow = nrows - 1;

    float4 acc0[8], acc1[8];
#pragma unroll
    for (int i = 0; i < 8; ++i) {
        acc0[i] = make_float4(0.f, 0.f, 0.f, 0.f);
        acc1[i] = make_float4(0.f, 0.f, 0.f, 0.f);
    }

    const float4* __restrict__ X4 = reinterpret_cast<const float4*>(X);
    int rIdx[8];
#pragma unroll
    for (int i = 0; i < 8; ++i) {
        int r = rowbase + i;
        rIdx[i] = r < lastrow ? r : lastrow;
    }

    for (int kk = 0; kk < 32; ++kk) {
        float4 x[8];
#pragma unroll
        for (int i = 0; i < 8; ++i) x[i] = X4[(size_t)rIdx[i] * 32 + kk];
#pragma unroll
        for (int j = 0; j < 4; ++j) {
            const int k = kk * 4 + j;
            const float4 w0 = *reinterpret_cast<const float4*>(&Wlds[k * OUT + tc * 4]);
            float4 w1;
            if constexpr (OUT == 128)
                w1 = *reinterpret_cast<const float4*>(&Wlds[k * OUT + 64 + tc * 4]);
#pragma unroll
            for (int i = 0; i < 8; ++i) {
                const float* xp = reinterpret_cast<const float*>(&x[i]);
                const float xs = xp[j];
                acc0[i].x += xs * w0.x;
                acc0[i].y += xs * w0.y;
                acc0[i].z += xs * w0.z;
                acc0[i].w += xs * w0.w;
                if constexpr (OUT == 128) {
                    acc1[i].x += xs * w1.x;
                    acc1[i].y += xs * w1.y;
                    acc1[i].z += xs * w1.z;
                    acc1[i].w += xs * w1.w;
                }
            }
        }
    }

    // Slab store: slab s is [nrows x 32] floats = nrows*8 float4.
    float4* __restrict__ C4 = reinterpret_cast<float4*>(C);
    const size_t slab = (size_t)nrows * 8;
    const int s0  = tc >> 3;     // slab for cols tc*4 (0..1)
    const int w0i = tc & 7;      // float4 index within 32-col slab row
#pragma unroll
    for (int i = 0; i < 8; ++i) {
        int r = rowbase + i;
        if (r < nrows) {
            const float nm = norm[r];
            float4 o0 = acc0[i];
            o0.x *= nm; o0.y *= nm; o0.z *= nm; o0.w *= nm;
            C4[(size_t)s0 * slab + (size_t)r * 8 + w0i] = o0;
            if constexpr (OUT == 128) {
                float4 o1 = acc1[i];
                o1.x *= nm; o1.y *= nm; o1.z *= nm; o1.w *= nm;
                C4[(size_t)(s0 + 2) * slab + (size_t)r * 8 + w0i] = o1;
            }
        }
    }
}

// ---------- Column-sliced gather-aggregate, 128 B granules ----------
// feat slice-major (F/32 slabs of [nnodes x 32] floats, 128 B rows).
// slice = blockIdx.x % NSLICE rides block->XCD round-robin (slab 6.4 MB, L2-fit).
// An 8-lane group owns one node: lane = float4 (16 B) of the 32-col slice ->
// one full 128 B cache line per edge per slice. Unroll 8 deep, clamped loads +
// masked accumulate. span = 96 -> exactly 3 nodes per group (balanced).
template <int F, bool RELU>
__global__ __launch_bounds__(256) void aggregate_sliced(const float* __restrict__ feat,
                                                        const int* __restrict__ rowptr,
                                                        const int* __restrict__ esrc,
                                                        const float* __restrict__ norm,
                                                        const float* __restrict__ b,
                                                        float* __restrict__ out,
                                                        int nnodes, int nchunks) {
    constexpr int NSLICE = F / 32;
    const int slice = blockIdx.x % NSLICE;
    const int chunk = blockIdx.x / NSLICE;
    const int span  = (nnodes + nchunks - 1) / nchunks;
    const int nbeg  = chunk * span;
    const int nend  = min(nnodes, nbeg + span);

    const int grp = threadIdx.x >> 3;   // 32 groups per block
    const int l8  = threadIdx.x & 7;    // float4 within the 32-col slice

    const float4* __restrict__ slab4 =
        reinterpret_cast<const float4*>(feat) + (size_t)slice * nnodes * 8;
    const float4 bb = reinterpret_cast<const float4*>(b)[slice * 8 + l8];

    for (int node = nbeg + grp; node < nend; node += 32) {
        const int beg = rowptr[node];
        const int end = rowptr[node + 1];

        float4 acc[8];
#pragma unroll
        for (int i = 0; i < 8; ++i) acc[i] = make_float4(0.f, 0.f, 0.f, 0.f);

        for (int e = beg; e < end; e += 8) {
            int idx[8];
#pragma unroll
            for (int i = 0; i < 8; ++i) {
                int ee = e + i;
                idx[i] = esrc[ee < end ? ee : end - 1];
            }
            float4 v[8];
#pragma unroll
            for (int i = 0; i < 8; ++i) v[i] = slab4[(size_t)idx[i] * 8 + l8];
#pragma unroll
            for (int i = 0; i < 8; ++i) {
                if (e + i < end) {
                    acc[i].x += v[i].x; acc[i].y += v[i].y;
                    acc[i].z += v[i].z; acc[i].w += v[i].w;
                }
            }
        }

        float4 a;
        a.x = ((acc[0].x + acc[1].x) + (acc[2].x + acc[3].x)) +
              ((acc[4].x + acc[5].x) + (acc[6].x + acc[7].x));
        a.y = ((acc[0].y + acc[1].y) + (acc[2].y + acc[3].y)) +
              ((acc[4].y + acc[5].y) + (acc[6].y + acc[7].y));
        a.z = ((acc[0].z + acc[1].z) + (acc[2].z + acc[3].z)) +
              ((acc[4].z + acc[5].z) + (acc[6].z + acc[7].z));
        a.w = ((acc[0].w + acc[1].w) + (acc[2].w + acc[3].w)) +
              ((acc[4].w + acc[5].w) + (acc[6].w + acc[7].w));

        const float nm = norm[node];
        float4 o;
        o.x = a.x * nm + bb.x;
        o.y = a.y * nm + bb.y;
        o.z = a.z * nm + bb.z;
        o.w = a.w * nm + bb.w;
        if (RELU) {
            o.x = fmaxf(o.x, 0.f); o.y = fmaxf(o.y, 0.f);
            o.z = fmaxf(o.z, 0.f); o.w = fmaxf(o.w, 0.f);
        }
        reinterpret_cast<float4*>(out)[(size_t)node * (F / 4) + slice * 8 + l8] = o;
    }
}

extern "C" void kernel_launch(void* const* d_in, const int* in_sizes, int n_in,
                              void* d_out, int out_size, void* d_ws, size_t ws_size,
                              hipStream_t stream) {
    const float* features = (const float*)d_in[0];
    const int*   src      = (const int*)d_in[1];
    const int*   dst      = (const int*)d_in[2];
    const float* W1 = (const float*)d_in[3];
    const float* b1 = (const float*)d_in[4];
    const float* W2 = (const float*)d_in[5];
    const float* b2 = (const float*)d_in[6];
    const float* W3 = (const float*)d_in[7];
    const float* b3 = (const float*)d_in[8];
    float* out = (float*)d_out;

    auto align256 = [](size_t x) { return (x + 255) / 256 * 256; };
    char* ws = (char*)d_ws;
    size_t off = 0;
    float* norm     = (float*)(ws + off); off += align256((size_t)N_NODES * 4);
    int*   cnt      = (int*)(ws + off);   off += align256((size_t)N_NODES * 4);
    int*   cursor   = (int*)(ws + off);   off += align256((size_t)N_NODES * 4);
    int*   rowptr   = (int*)(ws + off);   off += align256(((size_t)N_NODES + 1) * 4);
    int*   partials = (int*)(ws + off);   off += align256((size_t)SCAN_NB * 4);
    int*   esrc     = (int*)(ws + off);   off += align256((size_t)N_EDGES * 4);
    float* buf0     = (float*)(ws + off); off += (size_t)N_NODES * 128 * 4;
    float* buf1     = (float*)(ws + off);

    const int gemm_blocks = (N_NODES + 127) / 128;
    const int edge_blocks = (N_EDGES + 255) / 256;
    // span 96 nodes/chunk -> exactly 3 nodes per 8-lane group
    const int chunks = (N_NODES + 95) / 96;  // 521

    // ---- CSR build + norm ----
    hipMemsetAsync(cnt, 0, (size_t)N_NODES * 4, stream);
    count_kernel<<<edge_blocks, 256, 0, stream>>>(dst, cnt, N_EDGES);
    scanA_kernel<<<SCAN_NB, 256, 0, stream>>>(cnt, partials, N_NODES);
    scanB_kernel<<<1, 256, 0, stream>>>(partials, SCAN_NB);
    scanC_kernel<<<SCAN_NB, 256, 0, stream>>>(cnt, partials, rowptr, cursor, norm, N_NODES);
    fill_kernel<<<edge_blocks, 256, 0, stream>>>(src, dst, cursor, esrc, N_EDGES);

    // ---- Layer 1 ----
    gemm_rownorm<128><<<gemm_blocks, 256, 0, stream>>>(features, W1, norm, buf0, N_NODES);
    aggregate_sliced<128, true><<<chunks * 4, 256, 0, stream>>>(buf0, rowptr, esrc, norm, b1, buf1, N_NODES, chunks);

    // ---- Layer 2 ----
    gemm_rownorm<128><<<gemm_blocks, 256, 0, stream>>>(buf1, W2, norm, buf0, N_NODES);
    aggregate_sliced<128, true><<<chunks * 4, 256, 0, stream>>>(buf0, rowptr, esrc, norm, b2, buf1, N_NODES, chunks);

    // ---- Layer 3 (64 cols) ----
    gemm_rownorm<64><<<gemm_blocks, 256, 0, stream>>>(buf1, W3, norm, buf0, N_NODES);
    aggregate_sliced<64, false><<<chunks * 2, 256, 0, stream>>>(buf0, rowptr, esrc, norm, b3, out, N_NODES, chunks);
}

// Round 10
// 239.438 us; speedup vs baseline: 7.0830x; 1.2625x over previous
//
#include <hip/hip_runtime.h>

#define N_NODES 50000
#define N_EDGES 800000
#define NBUCKET 196           // ceil(N_NODES / 256); bucket b = dst in [b*256,(b+1)*256)
#define EPB 4096              // edges per block in bucket_count / partition (16/thread)
#define EDGE_BLKS ((N_EDGES + EPB - 1) / EPB)  // 196

__device__ __forceinline__ int wave_incl_scan(int v, int lane) {
#pragma unroll
    for (int off = 1; off < 64; off <<= 1) {
        int t = __shfl_up(v, off, 64);
        if (lane >= off) v += t;
    }
    return v;
}

// ---------- CSR build via bucket counting sort ----------

// Per-block LDS histogram by bucket, then <=196 global atomics per block.
__global__ __launch_bounds__(256) void bucket_count(const int* __restrict__ dst,
                                                    int* __restrict__ bcnt, int nedges) {
    __shared__ int h[NBUCKET];
    for (int i = threadIdx.x; i < NBUCKET; i += 256) h[i] = 0;
    __syncthreads();
    const int eb = blockIdx.x * EPB;
#pragma unroll
    for (int i = 0; i < 16; ++i) {
        int e = eb + i * 256 + threadIdx.x;
        if (e < nedges) atomicAdd(&h[dst[e] >> 8], 1);
    }
    __syncthreads();
    for (int i = threadIdx.x; i < NBUCKET; i += 256)
        if (h[i]) atomicAdd(&bcnt[i], h[i]);
}

// Exclusive scan of bucket totals (NBUCKET <= 256) -> bbase, bcursor.
__global__ __launch_bounds__(256) void bucket_scan(const int* __restrict__ bcnt,
                                                   int* __restrict__ bbase,
                                                   int* __restrict__ bcursor, int nb) {
    const int i = threadIdx.x;
    const int lane = i & 63;
    const int w = i >> 6;
    int v = (i < nb) ? bcnt[i] : 0;
    int s = wave_incl_scan(v, lane);
    __shared__ int ws[4];
    if (lane == 63) ws[w] = s;
    __syncthreads();
    int add = 0;
#pragma unroll
    for (int k = 0; k < 4; ++k)
        if (k < w) add += ws[k];
    if (i < nb) {
        int excl = s + add - v;
        bbase[i] = excl;
        bcursor[i] = excl;
    }
}

// Partition edges into bucket regions of etmp. Per block: LDS histogram,
// one global atomic per touched bucket to reserve a contiguous run, then
// scatter packed records ((dst&255)<<16 | src) into the runs.
__global__ __launch_bounds__(256) void partition_kernel(const int* __restrict__ src,
                                                        const int* __restrict__ dst,
                                                        int* __restrict__ bcursor,
                                                        int* __restrict__ etmp, int nedges) {
    __shared__ int h[NBUCKET];
    __shared__ int rbase[NBUCKET];
    for (int i = threadIdx.x; i < NBUCKET; i += 256) h[i] = 0;
    __syncthreads();

    const int eb = blockIdx.x * EPB;
    int d[16], s[16];
    bool ok[16];
#pragma unroll
    for (int i = 0; i < 16; ++i) {
        int e = eb + i * 256 + threadIdx.x;
        ok[i] = e < nedges;
        d[i] = ok[i] ? dst[e] : 0;
        s[i] = ok[i] ? src[e] : 0;
        if (ok[i]) atomicAdd(&h[d[i] >> 8], 1);
    }
    __syncthreads();
    for (int i = threadIdx.x; i < NBUCKET; i += 256) {
        rbase[i] = h[i] ? atomicAdd(&bcursor[i], h[i]) : 0;
        h[i] = 0;  // reuse as local cursor
    }
    __syncthreads();
#pragma unroll
    for (int i = 0; i < 16; ++i) {
        if (ok[i]) {
            int b = d[i] >> 8;
            int pos = rbase[b] + atomicAdd(&h[b], 1);
            etmp[pos] = ((d[i] & 255) << 16) | s[i];
        }
    }
}

// One block per bucket: per-node LDS histogram + scan over the block-private
// region -> rowptr, norm, and node-sorted esrc (full-line local writes).
__global__ __launch_bounds__(256) void bucket_build(const int* __restrict__ etmp,
                                                    const int* __restrict__ bbase,
                                                    int* __restrict__ rowptr,
                                                    int* __restrict__ esrc,
                                                    float* __restrict__ norm,
                                                    int nnodes, int nbuckets, int nedges) {
    const int b = blockIdx.x;
    const int nodebase = b * 256;
    const int nloc = min(256, nnodes - nodebase);
    const int ebeg = bbase[b];
    const int eend = (b + 1 < nbuckets) ? bbase[b + 1] : nedges;

    __shared__ int h[256];
    __shared__ int cur[256];
    h[threadIdx.x] = 0;
    __syncthreads();

    for (int e = ebeg + threadIdx.x; e < eend; e += 256)
        atomicAdd(&h[etmp[e] >> 16], 1);
    __syncthreads();

    const int lane = threadIdx.x & 63;
    const int w = threadIdx.x >> 6;
    int v = h[threadIdx.x];
    int sc = wave_incl_scan(v, lane);
    __shared__ int ws[4];
    if (lane == 63) ws[w] = sc;
    __syncthreads();
    int add = 0;
#pragma unroll
    for (int k = 0; k < 4; ++k)
        if (k < w) add += ws[k];
    const int excl = sc + add - v;

    if (threadIdx.x < nloc) {
        rowptr[nodebase + threadIdx.x] = ebeg + excl;
        norm[nodebase + threadIdx.x] = v > 0 ? rsqrtf((float)v) : 0.0f;
        if (nodebase + threadIdx.x == nnodes - 1) rowptr[nnodes] = ebeg + excl + v;
    }
    cur[threadIdx.x] = excl;
    __syncthreads();

    for (int e = ebeg + threadIdx.x; e < eend; e += 256) {
        int rec = etmp[e];
        int pos = ebeg + atomicAdd(&cur[rec >> 16], 1);
        esrc[pos] = rec & 0xFFFF;
    }
}

// ---------- GEMM with output row-scale, W staged in LDS ----------
// C_sliced[s][r][c] = norm[r] * sum_k X[r,k] * W[k, s*32+c]
// Output: F/32 slabs of [nrows x 32] floats (slice-major, 128 B rows).
template <int OUT>
__global__ __launch_bounds__(256) void gemm_rownorm(const float* __restrict__ X,
                                                    const float* __restrict__ W,
                                                    const float* __restrict__ norm,
                                                    float* __restrict__ C, int nrows) {
    __shared__ float Wlds[128 * OUT];

    const int t = threadIdx.x;

    constexpr int NSTAGE = (128 * OUT) / (256 * 4);
    {
        const float4* __restrict__ Wg = reinterpret_cast<const float4*>(W);
        float4* Wl = reinterpret_cast<float4*>(Wlds);
#pragma unroll
        for (int s = 0; s < NSTAGE; ++s) {
            int idx = s * 256 + t;
            Wl[idx] = Wg[idx];
        }
    }
    __syncthreads();

    const int tc = t & 15;
    const int tr = t >> 4;
    const int rowbase = blockIdx.x * 128 + tr * 8;
    const int lastrow = nrows - 1;

    float4 acc0[8], acc1[8];
#pragma unroll
    for (int i = 0; i < 8; ++i) {
        acc0[i] = make_float4(0.f, 0.f, 0.f, 0.f);
        acc1[i] = make_float4(0.f, 0.f, 0.f, 0.f);
    }

    const float4* __restrict__ X4 = reinterpret_cast<const float4*>(X);
    int rIdx[8];
#pragma unroll
    for (int i = 0; i < 8; ++i) {
        int r = rowbase + i;
        rIdx[i] = r < lastrow ? r : lastrow;
    }

    for (int kk = 0; kk < 32; ++kk) {
        float4 x[8];
#pragma unroll
        for (int i = 0; i < 8; ++i) x[i] = X4[(size_t)rIdx[i] * 32 + kk];
#pragma unroll
        for (int j = 0; j < 4; ++j) {
            const int k = kk * 4 + j;
            const float4 w0 = *reinterpret_cast<const float4*>(&Wlds[k * OUT + tc * 4]);
            float4 w1;
            if constexpr (OUT == 128)
                w1 = *reinterpret_cast<const float4*>(&Wlds[k * OUT + 64 + tc * 4]);
#pragma unroll
            for (int i = 0; i < 8; ++i) {
                const float* xp = reinterpret_cast<const float*>(&x[i]);
                const float xs = xp[j];
                acc0[i].x += xs * w0.x;
                acc0[i].y += xs * w0.y;
                acc0[i].z += xs * w0.z;
                acc0[i].w += xs * w0.w;
                if constexpr (OUT == 128) {
                    acc1[i].x += xs * w1.x;
                    acc1[i].y += xs * w1.y;
                    acc1[i].z += xs * w1.z;
                    acc1[i].w += xs * w1.w;
                }
            }
        }
    }

    float4* __restrict__ C4 = reinterpret_cast<float4*>(C);
    const size_t slab = (size_t)nrows * 8;
    const int s0  = tc >> 3;
    const int w0i = tc & 7;
#pragma unroll
    for (int i = 0; i < 8; ++i) {
        int r = rowbase + i;
        if (r < nrows) {
            const float nm = norm[r];
            float4 o0 = acc0[i];
            o0.x *= nm; o0.y *= nm; o0.z *= nm; o0.w *= nm;
            C4[(size_t)s0 * slab + (size_t)r * 8 + w0i] = o0;
            if constexpr (OUT == 128) {
                float4 o1 = acc1[i];
                o1.x *= nm; o1.y *= nm; o1.z *= nm; o1.w *= nm;
                C4[(size_t)(s0 + 2) * slab + (size_t)r * 8 + w0i] = o1;
            }
        }
    }
}

// ---------- Column-sliced gather-aggregate, 128 B granules ----------
template <int F, bool RELU>
__global__ __launch_bounds__(256) void aggregate_sliced(const float* __restrict__ feat,
                                                        const int* __restrict__ rowptr,
                                                        const int* __restrict__ esrc,
                                                        const float* __restrict__ norm,
                                                        const float* __restrict__ b,
                                                        float* __restrict__ out,
                                                        int nnodes, int nchunks) {
    constexpr int NSLICE = F / 32;
    const int slice = blockIdx.x % NSLICE;
    const int chunk = blockIdx.x / NSLICE;
    const int span  = (nnodes + nchunks - 1) / nchunks;
    const int nbeg  = chunk * span;
    const int nend  = min(nnodes, nbeg + span);

    const int grp = threadIdx.x >> 3;
    const int l8  = threadIdx.x & 7;

    const float4* __restrict__ slab4 =
        reinterpret_cast<const float4*>(feat) + (size_t)slice * nnodes * 8;
    const float4 bb = reinterpret_cast<const float4*>(b)[slice * 8 + l8];

    for (int node = nbeg + grp; node < nend; node += 32) {
        const int beg = rowptr[node];
        const int end = rowptr[node + 1];

        float4 acc[8];
#pragma unroll
        for (int i = 0; i < 8; ++i) acc[i] = make_float4(0.f, 0.f, 0.f, 0.f);

        for (int e = beg; e < end; e += 8) {
            int idx[8];
#pragma unroll
            for (int i = 0; i < 8; ++i) {
                int ee = e + i;
                idx[i] = esrc[ee < end ? ee : end - 1];
            }
            float4 v[8];
#pragma unroll
            for (int i = 0; i < 8; ++i) v[i] = slab4[(size_t)idx[i] * 8 + l8];
#pragma unroll
            for (int i = 0; i < 8; ++i) {
                if (e + i < end) {
                    acc[i].x += v[i].x; acc[i].y += v[i].y;
                    acc[i].z += v[i].z; acc[i].w += v[i].w;
                }
            }
        }

        float4 a;
        a.x = ((acc[0].x + acc[1].x) + (acc[2].x + acc[3].x)) +
              ((acc[4].x + acc[5].x) + (acc[6].x + acc[7].x));
        a.y = ((acc[0].y + acc[1].y) + (acc[2].y + acc[3].y)) +
              ((acc[4].y + acc[5].y) + (acc[6].y + acc[7].y));
        a.z = ((acc[0].z + acc[1].z) + (acc[2].z + acc[3].z)) +
              ((acc[4].z + acc[5].z) + (acc[6].z + acc[7].z));
        a.w = ((acc[0].w + acc[1].w) + (acc[2].w + acc[3].w)) +
              ((acc[4].w + acc[5].w) + (acc[6].w + acc[7].w));

        const float nm = norm[node];
        float4 o;
        o.x = a.x * nm + bb.x;
        o.y = a.y * nm + bb.y;
        o.z = a.z * nm + bb.z;
        o.w = a.w * nm + bb.w;
        if (RELU) {
            o.x = fmaxf(o.x, 0.f); o.y = fmaxf(o.y, 0.f);
            o.z = fmaxf(o.z, 0.f); o.w = fmaxf(o.w, 0.f);
        }
        reinterpret_cast<float4*>(out)[(size_t)node * (F / 4) + slice * 8 + l8] = o;
    }
}

extern "C" void kernel_launch(void* const* d_in, const int* in_sizes, int n_in,
                              void* d_out, int out_size, void* d_ws, size_t ws_size,
                              hipStream_t stream) {
    const float* features = (const float*)d_in[0];
    const int*   src      = (const int*)d_in[1];
    const int*   dst      = (const int*)d_in[2];
    const float* W1 = (const float*)d_in[3];
    const float* b1 = (const float*)d_in[4];
    const float* W2 = (const float*)d_in[5];
    const float* b2 = (const float*)d_in[6];
    const float* W3 = (const float*)d_in[7];
    const float* b3 = (const float*)d_in[8];
    float* out = (float*)d_out;

    auto align256 = [](size_t x) { return (x + 255) / 256 * 256; };
    char* ws = (char*)d_ws;
    size_t off = 0;
    float* norm    = (float*)(ws + off); off += align256((size_t)N_NODES * 4);
    int*   bcnt    = (int*)(ws + off);   off += align256((size_t)NBUCKET * 4);
    int*   bbase   = (int*)(ws + off);   off += align256((size_t)NBUCKET * 4);
    int*   bcursor = (int*)(ws + off);   off += align256((size_t)NBUCKET * 4);
    int*   rowptr  = (int*)(ws + off);   off += align256(((size_t)N_NODES + 1) * 4);
    int*   etmp    = (int*)(ws + off);   off += align256((size_t)N_EDGES * 4);
    int*   esrc    = (int*)(ws + off);   off += align256((size_t)N_EDGES * 4);
    float* buf0    = (float*)(ws + off); off += (size_t)N_NODES * 128 * 4;
    float* buf1    = (float*)(ws + off);

    const int gemm_blocks = (N_NODES + 127) / 128;
    const int chunks = (N_NODES + 95) / 96;  // span 96 -> 3 nodes per 8-lane group

    // ---- CSR build (bucket counting sort) + norm ----
    hipMemsetAsync(bcnt, 0, (size_t)NBUCKET * 4, stream);
    bucket_count<<<EDGE_BLKS, 256, 0, stream>>>(dst, bcnt, N_EDGES);
    bucket_scan<<<1, 256, 0, stream>>>(bcnt, bbase, bcursor, NBUCKET);
    partition_kernel<<<EDGE_BLKS, 256, 0, stream>>>(src, dst, bcursor, etmp, N_EDGES);
    bucket_build<<<NBUCKET, 256, 0, stream>>>(etmp, bbase, rowptr, esrc, norm,
                                              N_NODES, NBUCKET, N_EDGES);

    // ---- Layer 1 ----
    gemm_rownorm<128><<<gemm_blocks, 256, 0, stream>>>(features, W1, norm, buf0, N_NODES);
    aggregate_sliced<128, true><<<chunks * 4, 256, 0, stream>>>(buf0, rowptr, esrc, norm, b1, buf1, N_NODES, chunks);

    // ---- Layer 2 ----
    gemm_rownorm<128><<<gemm_blocks, 256, 0, stream>>>(buf1, W2, norm, buf0, N_NODES);
    aggregate_sliced<128, true><<<chunks * 4, 256, 0, stream>>>(buf0, rowptr, esrc, norm, b2, buf1, N_NODES, chunks);

    // ---- Layer 3 (64 cols) ----
    gemm_rownorm<64><<<gemm_blocks, 256, 0, stream>>>(buf1, W3, norm, buf0, N_NODES);
    aggregate_sliced<64, false><<<chunks * 2, 256, 0, stream>>>(buf0, rowptr, esrc, norm, b3, out, N_NODES, chunks);
}